// Round 2
// baseline (195.344 us; speedup 1.0000x reference)
//
#include <hip/hip_runtime.h>
#include <math.h>

#define D_DIM 512   // key dim == value dim == 512 (float4 x 128)

// ---- single-block counting sort: counts -> scan -> scatter, all in LDS ----
// LDS: cnt[n_q] + tsum[1024]  (n_q=4096 -> 20 KB)
__global__ __launch_bounds__(1024) void build_keylist(
        const int* __restrict__ tree_idx, int m_total, int n_q,
        int* __restrict__ offsets /*[n_q+1]*/, int* __restrict__ keylist) {
    extern __shared__ int lds[];
    int* cnt  = lds;        // n_q entries
    int* tsum = lds + n_q;  // 1024 entries
    const int tid = threadIdx.x;

    for (int i = tid; i < n_q; i += 1024) cnt[i] = 0;
    __syncthreads();
    for (int i = tid; i < m_total; i += 1024) atomicAdd(&cnt[tree_idx[i]], 1);
    __syncthreads();

    const int items = (n_q + 1023) >> 10;
    const int base  = tid * items;
    int local = 0;
    for (int i = 0; i < items; ++i) {
        int idx = base + i;
        if (idx < n_q) local += cnt[idx];
    }
    tsum[tid] = local;
    __syncthreads();
    for (int o = 1; o < 1024; o <<= 1) {
        int v = (tid >= o) ? tsum[tid - o] : 0;
        __syncthreads();
        tsum[tid] += v;
        __syncthreads();
    }
    int run = (tid == 0) ? 0 : tsum[tid - 1];
    for (int i = 0; i < items; ++i) {
        int idx = base + i;
        if (idx < n_q) {
            int c = cnt[idx];
            offsets[idx] = run;
            cnt[idx] = run;   // becomes the scatter cursor
            run += c;
        }
    }
    if (tid == 1023) offsets[n_q] = tsum[1023];
    __syncthreads();

    for (int i = tid; i < m_total; i += 1024) {
        int p = atomicAdd(&cnt[tree_idx[i]], 1);
        keylist[p] = i;
    }
}

// ---- main: one wave per query, 4 queries per 256-thread block -------------
// Register-only softmax (cos scores bounded by 1 -> exp without max shift).
__global__ __launch_bounds__(256, 4) void attn_main(
        const float* __restrict__ query, const float* __restrict__ keys,
        const float* __restrict__ values, const int* __restrict__ offsets,
        const int* __restrict__ keylist, float* __restrict__ att,
        float* __restrict__ colsum, int n_q) {
    const int wave = threadIdx.x >> 6;
    const int lane = threadIdx.x & 63;
    const int q = (blockIdx.x << 2) + wave;
    if (q >= n_q) return;

    const int off = offsets[q];
    const int nk  = offsets[q + 1] - off;

    const float4* qp = (const float4*)(query + (size_t)q * D_DIM);
    float4 qa = qp[lane];
    float4 qb = qp[lane + 64];
    float pq = qa.x*qa.x + qa.y*qa.y + qa.z*qa.z + qa.w*qa.w
             + qb.x*qb.x + qb.y*qb.y + qb.z*qb.z + qb.w*qb.w;

    float4* op = (float4*)(att + (size_t)q * D_DIM);

    if (nk <= 8 && nk > 0) {
        // ---- fast path: everything in registers, max MLP ----
        int m[8];
#pragma unroll
        for (int j = 0; j < 8; ++j) m[j] = (j < nk) ? keylist[off + j] : 0;

        float4 ka[8], kb[8];
#pragma unroll
        for (int j = 0; j < 8; ++j) {   // 16 independent global loads in flight
            const float4* kp = (const float4*)(keys + (size_t)m[j] * D_DIM);
            ka[j] = kp[lane];
            kb[j] = kp[lane + 64];
        }

        float pd[8], pk[8];
#pragma unroll
        for (int j = 0; j < 8; ++j) {
            pd[j] = qa.x*ka[j].x + qa.y*ka[j].y + qa.z*ka[j].z + qa.w*ka[j].w
                  + qb.x*kb[j].x + qb.y*kb[j].y + qb.z*kb[j].z + qb.w*kb[j].w;
            pk[j] = ka[j].x*ka[j].x + ka[j].y*ka[j].y + ka[j].z*ka[j].z + ka[j].w*ka[j].w
                  + kb[j].x*kb[j].x + kb[j].y*kb[j].y + kb[j].z*kb[j].z + kb[j].w*kb[j].w;
        }

        // batched reduction of 17 partials (ILP across the shuffle chain)
#pragma unroll
        for (int o = 32; o > 0; o >>= 1) {
            pq += __shfl_down(pq, o);
#pragma unroll
            for (int j = 0; j < 8; ++j) {
                pd[j] += __shfl_down(pd[j], o);
                pk[j] += __shfl_down(pk[j], o);
            }
        }
        const float qinv = 1.0f / fmaxf(sqrtf(__shfl(pq, 0)), 1e-12f);

        float e[8];
        float sum = 0.0f;
#pragma unroll
        for (int j = 0; j < 8; ++j) {
            float d  = __shfl(pd[j], 0);
            float k2 = __shfl(pk[j], 0);
            float kinv = 1.0f / fmaxf(sqrtf(k2), 1e-12f);
            float s = d * qinv * kinv;              // |s| <= 1: exp is safe bare
            e[j] = (j < nk) ? __expf(s) : 0.0f;
            sum += e[j];
        }
        const float inv = (sum > 0.0f) ? 1.0f / sum : 0.0f;

        if (lane == 0) {
#pragma unroll
            for (int j = 0; j < 8; ++j)
                if (j < nk) colsum[m[j]] = e[j] * inv;
        }

        float4 acc_a = make_float4(0.f, 0.f, 0.f, 0.f);
        float4 acc_b = make_float4(0.f, 0.f, 0.f, 0.f);
#pragma unroll
        for (int j = 0; j < 8; ++j) {   // 16 more independent loads
            const float4* vp = (const float4*)(values + (size_t)m[j] * D_DIM);
            float4 va = vp[lane];
            float4 vb = vp[lane + 64];
            float w = e[j] * inv;
            acc_a.x += w*va.x; acc_a.y += w*va.y; acc_a.z += w*va.z; acc_a.w += w*va.w;
            acc_b.x += w*vb.x; acc_b.y += w*vb.y; acc_b.z += w*vb.z; acc_b.w += w*vb.w;
        }
        op[lane]      = acc_a;
        op[lane + 64] = acc_b;
        return;
    }

    // ---- generic fallback (nk == 0 or nk > 8): two-pass recompute ----
#pragma unroll
    for (int o = 32; o > 0; o >>= 1) pq += __shfl_down(pq, o);
    const float qinv = 1.0f / fmaxf(sqrtf(__shfl(pq, 0)), 1e-12f);

    float sum = 0.0f;
    for (int j = 0; j < nk; ++j) {
        const float4* kp = (const float4*)(keys + (size_t)keylist[off + j] * D_DIM);
        float4 ka = kp[lane], kb = kp[lane + 64];
        float pd = qa.x*ka.x + qa.y*ka.y + qa.z*ka.z + qa.w*ka.w
                 + qb.x*kb.x + qb.y*kb.y + qb.z*kb.z + qb.w*kb.w;
        float pk = ka.x*ka.x + ka.y*ka.y + ka.z*ka.z + ka.w*ka.w
                 + kb.x*kb.x + kb.y*kb.y + kb.z*kb.z + kb.w*kb.w;
#pragma unroll
        for (int o = 32; o > 0; o >>= 1) { pd += __shfl_down(pd, o); pk += __shfl_down(pk, o); }
        float d = __shfl(pd, 0), k2 = __shfl(pk, 0);
        sum += __expf(d * qinv / fmaxf(sqrtf(k2), 1e-12f));
    }
    const float inv = (sum > 0.0f) ? 1.0f / sum : 0.0f;

    float4 acc_a = make_float4(0.f, 0.f, 0.f, 0.f);
    float4 acc_b = make_float4(0.f, 0.f, 0.f, 0.f);
    for (int j = 0; j < nk; ++j) {
        const int mj = keylist[off + j];
        const float4* kp = (const float4*)(keys + (size_t)mj * D_DIM);
        float4 ka = kp[lane], kb = kp[lane + 64];
        float pd = qa.x*ka.x + qa.y*ka.y + qa.z*ka.z + qa.w*ka.w
                 + qb.x*kb.x + qb.y*kb.y + qb.z*kb.z + qb.w*kb.w;
        float pk = ka.x*ka.x + ka.y*ka.y + ka.z*ka.z + ka.w*ka.w
                 + kb.x*kb.x + kb.y*kb.y + kb.z*kb.z + kb.w*kb.w;
#pragma unroll
        for (int o = 32; o > 0; o >>= 1) { pd += __shfl_down(pd, o); pk += __shfl_down(pk, o); }
        float d = __shfl(pd, 0), k2 = __shfl(pk, 0);
        float a = __expf(d * qinv / fmaxf(sqrtf(k2), 1e-12f)) * inv;
        if (lane == 0) colsum[mj] = a;
        const float4* vp = (const float4*)(values + (size_t)mj * D_DIM);
        float4 va = vp[lane], vb = vp[lane + 64];
        acc_a.x += a*va.x; acc_a.y += a*va.y; acc_a.z += a*va.z; acc_a.w += a*va.w;
        acc_b.x += a*vb.x; acc_b.y += a*vb.y; acc_b.z += a*vb.z; acc_b.w += a*vb.w;
    }
    op[lane]      = acc_a;
    op[lane + 64] = acc_b;
}

extern "C" void kernel_launch(void* const* d_in, const int* in_sizes, int n_in,
                              void* d_out, int out_size, void* d_ws, size_t ws_size,
                              hipStream_t stream) {
    const float* query    = (const float*)d_in[0];
    const float* keys     = (const float*)d_in[1];
    const float* values   = (const float*)d_in[2];
    const int*   tree_idx = (const int*)d_in[3];

    const int n_q     = in_sizes[0] / D_DIM;  // 4096
    const int m_total = in_sizes[3];          // 32768

    float* att    = (float*)d_out;
    float* colsum = att + (size_t)n_q * D_DIM;

    // workspace (ints): offsets[n_q+1] | keylist[m_total]
    int* offsets = (int*)d_ws;
    int* keylist = offsets + n_q + 1;

    const size_t lds_bytes = (size_t)(n_q + 1024) * sizeof(int);
    build_keylist<<<1, 1024, lds_bytes, stream>>>(tree_idx, m_total, n_q, offsets, keylist);
    attn_main<<<(n_q + 3) / 4, 256, 0, stream>>>(query, keys, values, offsets, keylist,
                                                 att, colsum, n_q);
}